// Round 1
// baseline (381.146 us; speedup 1.0000x reference)
//
#include <hip/hip_runtime.h>
#include <hip/hip_bf16.h>

// Grouped GEMM (MoE experts): out[t,o] = sum_k x[t,k] * W[e(t),o,k] + bias[e(t),o]
// E=64 experts, 4096 tokens/expert, D_IN = D_OUT = 512, f32 in/out.
// Strategy: bf16 MFMA (threshold permits), 128x128 tile, BK=32, double-buffered
// reg-staged LDS (f32->bf16 convert on the fly), XOR bank swizzle, XCD swizzle.

#define NEXP 64
#define DIN 512
#define DOUT 512
#define TPE 4096
#define BM 128
#define BN 128
#define BK 32
#define NKT (DIN / BK)  // 16

typedef __attribute__((ext_vector_type(8))) __bf16 bf16x8;
typedef __attribute__((ext_vector_type(4))) float f32x4;
typedef __attribute__((ext_vector_type(8))) unsigned short us8;

__device__ __forceinline__ unsigned short f2bf(float f) {
  unsigned u = __builtin_bit_cast(unsigned, f);
  u = (u + 0x7fffu + ((u >> 16) & 1u)) >> 16;  // RNE
  return (unsigned short)u;
}

__device__ __forceinline__ us8 pack8(f32x4 lo, f32x4 hi) {
  us8 r;
  r[0] = f2bf(lo[0]); r[1] = f2bf(lo[1]); r[2] = f2bf(lo[2]); r[3] = f2bf(lo[3]);
  r[4] = f2bf(hi[0]); r[5] = f2bf(hi[1]); r[6] = f2bf(hi[2]); r[7] = f2bf(hi[3]);
  return r;
}

__global__ __launch_bounds__(256)
void moe_grouped_gemm(const float* __restrict__ x,
                      const float* __restrict__ w,
                      const float* __restrict__ bias,
                      float* __restrict__ out) {
  // LDS: [2 buffers][128 rows][4 kgroups of 8 bf16] -> us8 granularity
  __shared__ us8 sA[2][512];
  __shared__ us8 sB[2][512];

  // XCD-aware swizzle: 8192 blocks = 8 XCDs x 1024 contiguous each.
  int bid = blockIdx.x;
  int swz = (bid & 7) * 1024 + (bid >> 3);
  int e  = swz >> 7;        // 128 blocks per expert
  int rr = swz & 127;
  int mt = rr >> 2;         // 32 M-tiles, outer (A-panel reused by 4 consecutive)
  int nt = rr & 3;          // 4 N-tiles, inner

  const int t    = threadIdx.x;
  const int lane = t & 63;
  const int wave = t >> 6;
  const int wm   = wave >> 1;   // 2x2 wave grid, each wave 64x64
  const int wn   = wave & 1;
  const int r15  = lane & 15;
  const int kg   = lane >> 4;
  // fragment-read slot: row = base + r15, kgroup swizzled by ((row>>1)&3);
  // bases are multiples of 16 so the swizzle term depends only on r15.
  const int rs = r15 * 4 + (kg ^ ((r15 >> 1) & 3));

  // staging: 512 chunks (128 rows x 4 kgroups) per tile, 2 chunks/thread
  const int row0  = t >> 2;   // 0..63
  const int kg0   = t & 3;
  const int slot0 = row0 * 4 + (kg0 ^ ((row0 >> 1) & 3));
  const int slot1 = slot0 + 256;  // row0+64: (row>>1)&3 unchanged (+32 ≡ 0 mod 4)

  const float* Ab = x + ((size_t)e * TPE + (size_t)mt * BM) * DIN;
  const float* Bb = w + ((size_t)e * DOUT + (size_t)nt * BN) * DIN;
  const int offA0 = row0 * DIN + kg0 * 8;
  const int offA1 = offA0 + 64 * DIN;

  f32x4 a0l, a0h, a1l, a1h, b0l, b0h, b1l, b1h;

  auto LOAD = [&](int kt) {
    const float* pa0 = Ab + offA0 + kt * BK;
    const float* pa1 = Ab + offA1 + kt * BK;
    const float* pb0 = Bb + offA0 + kt * BK;
    const float* pb1 = Bb + offA1 + kt * BK;
    a0l = *(const f32x4*)(pa0); a0h = *(const f32x4*)(pa0 + 4);
    a1l = *(const f32x4*)(pa1); a1h = *(const f32x4*)(pa1 + 4);
    b0l = *(const f32x4*)(pb0); b0h = *(const f32x4*)(pb0 + 4);
    b1l = *(const f32x4*)(pb1); b1h = *(const f32x4*)(pb1 + 4);
  };
  auto STORE = [&](int buf) {
    sA[buf][slot0] = pack8(a0l, a0h);
    sA[buf][slot1] = pack8(a1l, a1h);
    sB[buf][slot0] = pack8(b0l, b0h);
    sB[buf][slot1] = pack8(b1l, b1h);
  };

  f32x4 acc[4][4];
#pragma unroll
  for (int m = 0; m < 4; ++m)
#pragma unroll
    for (int n = 0; n < 4; ++n) acc[m][n] = (f32x4)0.f;

  LOAD(0);
  STORE(0);
  __syncthreads();

  int cur = 0;
  for (int kt = 0; kt < NKT; ++kt) {
    if (kt + 1 < NKT) LOAD(kt + 1);  // issue-early: latency hides under MFMA

    bf16x8 af[4], bfr[4];
#pragma unroll
    for (int m = 0; m < 4; ++m)
      af[m] = __builtin_bit_cast(bf16x8, sA[cur][wm * 256 + m * 64 + rs]);
#pragma unroll
    for (int n = 0; n < 4; ++n)
      bfr[n] = __builtin_bit_cast(bf16x8, sB[cur][wn * 256 + n * 64 + rs]);

#pragma unroll
    for (int m = 0; m < 4; ++m)
#pragma unroll
      for (int n = 0; n < 4; ++n)
        acc[m][n] = __builtin_amdgcn_mfma_f32_16x16x32_bf16(
            af[m], bfr[n], acc[m][n], 0, 0, 0);

    if (kt + 1 < NKT) {
      STORE(cur ^ 1);   // write-late into the other buffer
      __syncthreads();
    }
    cur ^= 1;
  }

  // epilogue: C/D layout col = lane&15, row = (lane>>4)*4 + j  [m89/m91]
  float bv[4];
  const float* bp = bias + (size_t)e * DOUT + nt * BN + wn * 64 + r15;
#pragma unroll
  for (int n = 0; n < 4; ++n) bv[n] = bp[n * 16];

  const int q4 = (lane >> 4) * 4;
  float* Cb = out + ((size_t)e * TPE + (size_t)mt * BM + wm * 64) * DOUT
              + nt * BN + wn * 64;
#pragma unroll
  for (int m = 0; m < 4; ++m) {
#pragma unroll
    for (int j = 0; j < 4; ++j) {
      float* pr = Cb + (size_t)(m * 16 + q4 + j) * DOUT;
#pragma unroll
      for (int n = 0; n < 4; ++n)
        pr[n * 16 + r15] = acc[m][n][j] + bv[n];
    }
  }
}

extern "C" void kernel_launch(void* const* d_in, const int* in_sizes, int n_in,
                              void* d_out, int out_size, void* d_ws, size_t ws_size,
                              hipStream_t stream) {
  const float* x    = (const float*)d_in[0];
  // d_in[1] = num_experts_per_token (int64): balanced by construction, unused
  const float* w    = (const float*)d_in[2];
  const float* bias = (const float*)d_in[3];
  float* out        = (float*)d_out;

  dim3 grid(NEXP * (TPE / BM) * (DOUT / BN));  // 8192
  dim3 block(256);
  hipLaunchKernelGGL(moe_grouped_gemm, grid, block, 0, stream, x, w, bias, out);
}

// Round 2
// 370.847 us; speedup vs baseline: 1.0278x; 1.0278x over previous
//
#include <hip/hip_runtime.h>
#include <hip/hip_bf16.h>

// Grouped GEMM (MoE experts): out[t,o] = sum_k x[t,k] * W[e(t),o,k] + bias[e(t),o]
// E=64 experts, 4096 tokens/expert, D_IN = D_OUT = 512, f32 in/out.
// bf16 MFMA, 128x128 tile, BK=32, double-buffered reg-staged LDS with native
// (__bf16) casts (compiler emits v_cvt_pk_bf16_f32), XOR bank swizzle, XCD swizzle.

#define NEXP 64
#define DIN 512
#define DOUT 512
#define TPE 4096
#define BM 128
#define BN 128
#define BK 32
#define NKT (DIN / BK)  // 16

typedef __attribute__((ext_vector_type(8))) __bf16 bf16x8;
typedef __attribute__((ext_vector_type(4))) float f32x4;

__device__ __forceinline__ bf16x8 cvt8(f32x4 lo, f32x4 hi) {
  bf16x8 r;
  r[0] = (__bf16)lo[0]; r[1] = (__bf16)lo[1];
  r[2] = (__bf16)lo[2]; r[3] = (__bf16)lo[3];
  r[4] = (__bf16)hi[0]; r[5] = (__bf16)hi[1];
  r[6] = (__bf16)hi[2]; r[7] = (__bf16)hi[3];
  return r;
}

__global__ __launch_bounds__(256)
void moe_grouped_gemm(const float* __restrict__ x,
                      const float* __restrict__ w,
                      const float* __restrict__ bias,
                      float* __restrict__ out) {
  // LDS: [2 buffers][128 rows][4 kgroups of 8 bf16]
  __shared__ bf16x8 sA[2][512];
  __shared__ bf16x8 sB[2][512];

  // XCD-aware swizzle: 8192 blocks = 8 XCDs x 1024 contiguous each.
  int bid = blockIdx.x;
  int swz = (bid & 7) * 1024 + (bid >> 3);
  int e  = swz >> 7;        // 128 blocks per expert
  int rr = swz & 127;
  int mt = rr >> 2;         // 32 M-tiles, outer (A-panel reused by 4 consecutive)
  int nt = rr & 3;          // 4 N-tiles, inner

  const int t    = threadIdx.x;
  const int lane = t & 63;
  const int wave = t >> 6;
  const int wm   = wave >> 1;   // 2x2 wave grid, each wave 64x64
  const int wn   = wave & 1;
  const int r15  = lane & 15;
  const int kg   = lane >> 4;
  // fragment-read slot: row = base + r15, kgroup swizzled by ((row>>1)&3);
  // bases are multiples of 16 so the swizzle term depends only on r15.
  const int rs = r15 * 4 + (kg ^ ((r15 >> 1) & 3));

  // staging: 512 chunks (128 rows x 4 kgroups) per tile, 2 chunks/thread
  const int row0  = t >> 2;   // 0..63
  const int kg0   = t & 3;
  const int slot0 = row0 * 4 + (kg0 ^ ((row0 >> 1) & 3));
  const int slot1 = slot0 + 256;  // row0+64: (row>>1)&3 unchanged (+64 ≡ 0 mod 4 after >>1)

  const float* Ab = x + ((size_t)e * TPE + (size_t)mt * BM) * DIN;
  const float* Bb = w + ((size_t)e * DOUT + (size_t)nt * BN) * DIN;
  const int offA0 = row0 * DIN + kg0 * 8;
  const int offA1 = offA0 + 64 * DIN;

  f32x4 a0l, a0h, a1l, a1h, b0l, b0h, b1l, b1h;

  auto LOAD = [&](int kt) {
    const float* pa0 = Ab + offA0 + kt * BK;
    const float* pa1 = Ab + offA1 + kt * BK;
    const float* pb0 = Bb + offA0 + kt * BK;
    const float* pb1 = Bb + offA1 + kt * BK;
    a0l = *(const f32x4*)(pa0); a0h = *(const f32x4*)(pa0 + 4);
    a1l = *(const f32x4*)(pa1); a1h = *(const f32x4*)(pa1 + 4);
    b0l = *(const f32x4*)(pb0); b0h = *(const f32x4*)(pb0 + 4);
    b1l = *(const f32x4*)(pb1); b1h = *(const f32x4*)(pb1 + 4);
  };
  auto STORE = [&](int buf) {
    sA[buf][slot0] = cvt8(a0l, a0h);
    sA[buf][slot1] = cvt8(a1l, a1h);
    sB[buf][slot0] = cvt8(b0l, b0h);
    sB[buf][slot1] = cvt8(b1l, b1h);
  };

  f32x4 acc[4][4];
#pragma unroll
  for (int m = 0; m < 4; ++m)
#pragma unroll
    for (int n = 0; n < 4; ++n) acc[m][n] = (f32x4)0.f;

  LOAD(0);
  STORE(0);
  __syncthreads();

  int cur = 0;
  for (int kt = 0; kt < NKT; ++kt) {
    if (kt + 1 < NKT) LOAD(kt + 1);  // issue-early: latency hides under MFMA

    bf16x8 af[4], bfr[4];
#pragma unroll
    for (int m = 0; m < 4; ++m)
      af[m] = sA[cur][wm * 256 + m * 64 + rs];
#pragma unroll
    for (int n = 0; n < 4; ++n)
      bfr[n] = sB[cur][wn * 256 + n * 64 + rs];

#pragma unroll
    for (int m = 0; m < 4; ++m)
#pragma unroll
      for (int n = 0; n < 4; ++n)
        acc[m][n] = __builtin_amdgcn_mfma_f32_16x16x32_bf16(
            af[m], bfr[n], acc[m][n], 0, 0, 0);

    if (kt + 1 < NKT) {
      STORE(cur ^ 1);   // write-late into the other buffer
      __syncthreads();
    }
    cur ^= 1;
  }

  // epilogue: C/D layout col = lane&15, row = (lane>>4)*4 + j  [m89/m91]
  float bv[4];
  const float* bp = bias + (size_t)e * DOUT + nt * BN + wn * 64 + r15;
#pragma unroll
  for (int n = 0; n < 4; ++n) bv[n] = bp[n * 16];

  const int q4 = (lane >> 4) * 4;
  float* Cb = out + ((size_t)e * TPE + (size_t)mt * BM + wm * 64) * DOUT
              + nt * BN + wn * 64;
#pragma unroll
  for (int m = 0; m < 4; ++m) {
#pragma unroll
    for (int j = 0; j < 4; ++j) {
      float* pr = Cb + (size_t)(m * 16 + q4 + j) * DOUT;
#pragma unroll
      for (int n = 0; n < 4; ++n)
        pr[n * 16 + r15] = acc[m][n][j] + bv[n];
    }
  }
}

extern "C" void kernel_launch(void* const* d_in, const int* in_sizes, int n_in,
                              void* d_out, int out_size, void* d_ws, size_t ws_size,
                              hipStream_t stream) {
  const float* x    = (const float*)d_in[0];
  // d_in[1] = num_experts_per_token (int64): balanced by construction, unused
  const float* w    = (const float*)d_in[2];
  const float* bias = (const float*)d_in[3];
  float* out        = (float*)d_out;

  dim3 grid(NEXP * (TPE / BM) * (DOUT / BN));  // 8192
  dim3 block(256);
  hipLaunchKernelGGL(moe_grouped_gemm, grid, block, 0, stream, x, w, bias, out);
}